// Round 1
// baseline (4632.171 us; speedup 1.0000x reference)
//
#include <hip/hip_runtime.h>
#include <stdint.h>

typedef __attribute__((ext_vector_type(8))) short short8;
typedef __attribute__((ext_vector_type(4))) float floatx4;

#define NB 512
#define T1 127
#define ENC 256
#define HD 256
// LSTM tiling: 8 batch-tiles x 32 h-tiles = 256 blocks, 64 batches x 8 h per block
#define BT 8
#define HT 32
#define BTILE 64

// workspace offsets (bytes)
#define WHI_OFF   0u            // 1024*256 ushort = 524288
#define WLO_OFF   524288u
#define DHI_OFF   1048576u      // 2 bufs x (512*256 ushort = 262144B)
#define DLO_OFF   1572864u
#define WEFF_OFF  2097152u      // 256 floats
#define FLAGS_OFF 2101248u      // 256 u32
#define YT_OFF    2105344u      // 512*128 floats = 262144B
#define CTX_OFF   2367488u      // 512*256 floats = 524288B
#define DT_OFF    2891776u      // 512*256 floats = 524288B

__device__ __forceinline__ void split_bf16(float x, unsigned& hi, unsigned& lo) {
    unsigned u = __float_as_uint(x);
    hi = u >> 16;
    float hf = __uint_as_float(hi << 16);
    float r = x - hf;
    unsigned ur = __float_as_uint(r);
    lo = (ur + 0x7fffu + ((ur >> 16) & 1u)) >> 16;
}

// ---------------- k_prep: weight collapse + W_hh hi/lo split + init ----------------
__global__ __launch_bounds__(256) void k_prep(const float* __restrict__ W1,
                                              const float* __restrict__ W2,
                                              const float* __restrict__ W_hh,
                                              char* __restrict__ ws) {
    const int tid = threadIdx.x, bid = blockIdx.x;
    ushort* Whi = (ushort*)(ws + WHI_OFF);
    ushort* Wlo = (ushort*)(ws + WLO_OFF);
    // split W_hh (1024x256): each thread one float4
    {
        const int i4 = bid * 256 + tid;   // 0..65535
        float4 v = ((const float4*)W_hh)[i4];
        float vv[4] = {v.x, v.y, v.z, v.w};
        unsigned h[4], l[4];
        #pragma unroll
        for (int j = 0; j < 4; ++j) split_bf16(vv[j], h[j], l[j]);
        *(ushort4*)(Whi + i4 * 4) = make_ushort4((ushort)h[0], (ushort)h[1], (ushort)h[2], (ushort)h[3]);
        *(ushort4*)(Wlo + i4 * 4) = make_ushort4((ushort)l[0], (ushort)l[1], (ushort)l[2], (ushort)l[3]);
    }
    // zero d buffer 0 (hi & lo planes, 262144B each = 16384 uint4 each)
    {
        const int z = bid * 64 + (tid & 63);
        if (tid < 64)        ((uint4*)(ws + DHI_OFF))[z] = make_uint4(0, 0, 0, 0);
        else if (tid < 128)  ((uint4*)(ws + DLO_OFF))[z] = make_uint4(0, 0, 0, 0);
    }
    if (bid == 0) {
        // flags
        ((unsigned*)(ws + FLAGS_OFF))[tid] = 0u;
        // collapsed attention weight: weff[e] = sum_j W2[j] * W1[j,512+e]
        float acc = 0.f;
        for (int j = 0; j < 128; ++j)
            acc = fmaf(W2[j], W1[j * 768 + 512 + tid], acc);
        ((float*)(ws + WEFF_OFF))[tid] = acc;
    }
}

// ---------------- k_attn: scores -> softmax -> context -> y_tilde ----------------
__global__ __launch_bounds__(256) void k_attn(const float* __restrict__ X,
                                              const float* __restrict__ y_prev,
                                              const float* __restrict__ W_fc,
                                              const float* __restrict__ b_fc,
                                              char* __restrict__ ws) {
    __shared__ float s_lds[128];
    __shared__ float beta[128];
    __shared__ float red[256];
    const int b = blockIdx.x, tid = threadIdx.x;
    const int w = tid >> 6, lane = tid & 63;
    const float* Xb = X + (size_t)b * T1 * ENC;
    const float* weff = (const float*)(ws + WEFF_OFF);
    const float4 w4 = ((const float4*)weff)[lane];
    for (int i = 0; i < 32; ++i) {
        int t = w * 32 + i;
        if (t >= T1) break;
        float4 x4 = ((const float4*)(Xb + t * ENC))[lane];
        float a = x4.x * w4.x + x4.y * w4.y + x4.z * w4.z + x4.w * w4.w;
        for (int m = 32; m >= 1; m >>= 1) a += __shfl_xor(a, m, 64);
        if (lane == 0) s_lds[t] = a;
    }
    __syncthreads();
    if (w == 0) {
        float v0 = s_lds[lane];
        float v1 = (lane + 64 < T1) ? s_lds[lane + 64] : -1e30f;
        float mx = fmaxf(v0, v1);
        for (int m = 32; m >= 1; m >>= 1) mx = fmaxf(mx, __shfl_xor(mx, m, 64));
        float e0 = __expf(v0 - mx);
        float e1 = (lane + 64 < T1) ? __expf(v1 - mx) : 0.f;
        float s = e0 + e1;
        for (int m = 32; m >= 1; m >>= 1) s += __shfl_xor(s, m, 64);
        float inv = 1.f / s;
        beta[lane] = e0 * inv;
        if (lane + 64 < T1) beta[lane + 64] = e1 * inv;
    }
    __syncthreads();
    // context[b, tid]
    float acc = 0.f;
    for (int t = 0; t < T1; ++t) acc = fmaf(beta[t], Xb[t * ENC + tid], acc);
    ((float*)(ws + CTX_OFF))[b * ENC + tid] = acc;
    // u = W_fc[0:256] . context + b_fc
    red[tid] = acc * W_fc[tid];
    __syncthreads();
    for (int s = 128; s >= 1; s >>= 1) { if (tid < s) red[tid] += red[tid + s]; __syncthreads(); }
    const float u = red[0] + b_fc[0];
    const float wy = W_fc[256];
    if (tid < T1)
        ((float*)(ws + YT_OFF))[b * 128 + tid] = u + wy * y_prev[b * T1 + tid];
}

// ---------------- k_lstm: persistent sequential LSTM ----------------
__global__ __launch_bounds__(256, 1) void k_lstm(const float* __restrict__ W_ih,
                                                 const float* __restrict__ b_ih,
                                                 const float* __restrict__ b_hh,
                                                 char* __restrict__ ws) {
    __shared__ __align__(16) unsigned char lds[65536];  // d hi-plane [0,32K), d lo-plane [32K,64K); aliased as gbuf

    const int tid = threadIdx.x;
    const int bid = blockIdx.x;
    const int bi = bid >> 5, hj = bid & 31;
    const int b0 = bi * BTILE;
    const int hbase = hj * 8;
    const int w = tid >> 6, lane = tid & 63;
    const int n16 = lane & 15, q = lane >> 4;
    const int ntile = w >> 1, mpair = w & 1;

    const ushort* Whi = (const ushort*)(ws + WHI_OFF);
    const ushort* Wlo = (const ushort*)(ws + WLO_OFF);
    ushort* dhiG[2] = {(ushort*)(ws + DHI_OFF), (ushort*)(ws + DHI_OFF + 262144u)};
    ushort* dloG[2] = {(ushort*)(ws + DLO_OFF), (ushort*)(ws + DLO_OFF + 262144u)};
    const float* yt = (const float*)(ws + YT_OFF);
    unsigned* flags = (unsigned*)(ws + FLAGS_OFF);
    float* dT = (float*)(ws + DT_OFF);
    float* gbuf = (float*)lds;   // [64][33] fp32, written after all MFMA LDS reads done

    // B-fragments (W slice) in registers, loaded once.
    short8 bfh[8], bfl[8];
    {
        const int p = ntile * 16 + n16;                    // packed row 0..31
        const int row = (p >> 3) * HD + hbase + (p & 7);   // gate*256 + h
        const ushort* bh = Whi + row * 256 + q * 8;
        const ushort* bl = Wlo + row * 256 + q * 8;
        #pragma unroll
        for (int kt = 0; kt < 8; ++kt) {
            bfh[kt] = *(const short8*)(bh + kt * 32);
            bfl[kt] = *(const short8*)(bl + kt * 32);
        }
    }
    // per-thread cell constants: 2 cells (cb, hh2) and (cb, hh2+1)
    const int cb = tid >> 2;                // local batch 0..63
    const int hh2 = (tid & 3) * 2;
    const int bg = b0 + cb;                 // global batch
    float wihr[2][4], bihr[2][4];
    #pragma unroll
    for (int j = 0; j < 2; ++j)
        #pragma unroll
        for (int g = 0; g < 4; ++g) {
            int row = g * HD + hbase + hh2 + j;
            wihr[j][g] = W_ih[row];
            bihr[j][g] = b_ih[row] + b_hh[row];
        }
    float c0 = 0.f, c1 = 0.f;

    for (int t = 1; t <= T1; ++t) {
        // wait for previous step's d from the other 31 blocks of this batch group
        if (t > 1) {
            const unsigned tgt = (unsigned)(t - 1);
            const unsigned fidx = bi * 32 + (lane & 31);
            while (!__all((int)(__hip_atomic_load(&flags[fidx], __ATOMIC_RELAXED,
                                                  __HIP_MEMORY_SCOPE_AGENT) >= tgt))) { }
            __syncthreads();
            __builtin_amdgcn_fence(__ATOMIC_ACQUIRE, "agent");
        }
        // stage d tile (64 rows x 256) hi+lo into LDS, XOR-swizzled 16B chunks
        {
            const int buf = (t - 1) & 1;
            const uint4* gh = (const uint4*)(dhiG[buf] + b0 * 256);
            const uint4* gl = (const uint4*)(dloG[buf] + b0 * 256);
            #pragma unroll 4
            for (int i = 0; i < 8; ++i) {
                uint4 vh = gh[i * 256 + tid];
                uint4 vl = gl[i * 256 + tid];
                const int r = i * 8 + (tid >> 5);
                const int cc = (tid & 31) ^ (r & 7);
                *(uint4*)(lds + r * 512 + cc * 16) = vh;
                *(uint4*)(lds + 32768 + r * 512 + cc * 16) = vl;
            }
        }
        __syncthreads();
        // MFMA: gates[64b x 32p] += d @ Wslice^T  (hi*hi + hi*lo + lo*hi)
        floatx4 acc0 = {0.f, 0.f, 0.f, 0.f}, acc1 = {0.f, 0.f, 0.f, 0.f};
        const int r0 = (mpair * 2) * 16 + n16;
        const int r1 = r0 + 16;
        #pragma unroll
        for (int kt = 0; kt < 8; ++kt) {
            const int chunk = kt * 4 + q;
            short8 a0h = *(const short8*)(lds + r0 * 512 + ((chunk ^ (r0 & 7)) * 16));
            short8 a0l = *(const short8*)(lds + 32768 + r0 * 512 + ((chunk ^ (r0 & 7)) * 16));
            short8 a1h = *(const short8*)(lds + r1 * 512 + ((chunk ^ (r1 & 7)) * 16));
            short8 a1l = *(const short8*)(lds + 32768 + r1 * 512 + ((chunk ^ (r1 & 7)) * 16));
            acc0 = __builtin_amdgcn_mfma_f32_16x16x32_bf16(a0h, bfh[kt], acc0, 0, 0, 0);
            acc0 = __builtin_amdgcn_mfma_f32_16x16x32_bf16(a0h, bfl[kt], acc0, 0, 0, 0);
            acc0 = __builtin_amdgcn_mfma_f32_16x16x32_bf16(a0l, bfh[kt], acc0, 0, 0, 0);
            acc1 = __builtin_amdgcn_mfma_f32_16x16x32_bf16(a1h, bfh[kt], acc1, 0, 0, 0);
            acc1 = __builtin_amdgcn_mfma_f32_16x16x32_bf16(a1h, bfl[kt], acc1, 0, 0, 0);
            acc1 = __builtin_amdgcn_mfma_f32_16x16x32_bf16(a1l, bfh[kt], acc1, 0, 0, 0);
        }
        __syncthreads();   // all LDS reads done; safe to alias as gbuf
        // D layout: col = lane&15, row = (lane>>4)*4 + reg
        {
            const int mb = (mpair * 2) * 16 + q * 4;
            const int col = ntile * 16 + n16;
            #pragma unroll
            for (int r = 0; r < 4; ++r) {
                gbuf[(mb + r) * 33 + col] = acc0[r];
                gbuf[(mb + 16 + r) * 33 + col] = acc1[r];
            }
        }
        __syncthreads();
        // LSTM cell for this thread's 2 cells
        {
            const float ytv = yt[bg * 128 + (t - 1)];
            float dnew[2];
            #pragma unroll
            for (int j = 0; j < 2; ++j) {
                const int hh = hh2 + j;
                float pi = gbuf[cb * 33 + hh]      + ytv * wihr[j][0] + bihr[j][0];
                float pf = gbuf[cb * 33 + 8 + hh]  + ytv * wihr[j][1] + bihr[j][1];
                float pg = gbuf[cb * 33 + 16 + hh] + ytv * wihr[j][2] + bihr[j][2];
                float po = gbuf[cb * 33 + 24 + hh] + ytv * wihr[j][3] + bihr[j][3];
                float ig = 1.f / (1.f + __expf(-pi));
                float fg = 1.f / (1.f + __expf(-pf));
                float gg = tanhf(pg);
                float og = 1.f / (1.f + __expf(-po));
                float& c = j ? c1 : c0;
                c = fg * c + ig * gg;
                dnew[j] = og * tanhf(c);
            }
            if (t < T1) {
                const int buf = t & 1;
                unsigned h0b, l0b, h1b, l1b;
                split_bf16(dnew[0], h0b, l0b);
                split_bf16(dnew[1], h1b, l1b);
                const int hoff = bg * 256 + hbase + hh2;
                *(unsigned*)(dhiG[buf] + hoff) = h0b | (h1b << 16);
                *(unsigned*)(dloG[buf] + hoff) = l0b | (l1b << 16);
                __builtin_amdgcn_fence(__ATOMIC_RELEASE, "agent");
                __syncthreads();
                if (tid == 0)
                    __hip_atomic_store(&flags[bid], (unsigned)t, __ATOMIC_RELAXED,
                                       __HIP_MEMORY_SCOPE_AGENT);
            } else {
                *(float2*)(dT + bg * 256 + hbase + hh2) = make_float2(dnew[0], dnew[1]);
            }
        }
    }
}

// ---------------- k_final: y_pred = W_final . [dT, context] + b ----------------
__global__ __launch_bounds__(256) void k_final(const float* __restrict__ W_final,
                                               const float* __restrict__ b_final,
                                               float* __restrict__ out,
                                               char* __restrict__ ws) {
    __shared__ float red[256];
    const int b = blockIdx.x, tid = threadIdx.x;
    const float* dT = (const float*)(ws + DT_OFF);
    const float* ctx = (const float*)(ws + CTX_OFF);
    float v = W_final[tid] * dT[b * 256 + tid] + W_final[256 + tid] * ctx[b * 256 + tid];
    red[tid] = v;
    __syncthreads();
    for (int s = 128; s >= 1; s >>= 1) { if (tid < s) red[tid] += red[tid + s]; __syncthreads(); }
    if (tid == 0) out[b] = red[0] + b_final[0];
}

extern "C" void kernel_launch(void* const* d_in, const int* in_sizes, int n_in,
                              void* d_out, int out_size, void* d_ws, size_t ws_size,
                              hipStream_t stream) {
    const float* X      = (const float*)d_in[0];
    const float* y_prev = (const float*)d_in[1];
    const float* W1     = (const float*)d_in[2];
    const float* W2     = (const float*)d_in[4];
    const float* W_fc   = (const float*)d_in[6];
    const float* b_fc   = (const float*)d_in[7];
    const float* W_ih   = (const float*)d_in[8];
    const float* W_hh   = (const float*)d_in[9];
    const float* b_ih   = (const float*)d_in[10];
    const float* b_hh   = (const float*)d_in[11];
    const float* W_fin  = (const float*)d_in[12];
    const float* b_fin  = (const float*)d_in[13];
    char* ws = (char*)d_ws;

    hipLaunchKernelGGL(k_prep,  dim3(256), dim3(256), 0, stream, W1, W2, W_hh, ws);
    hipLaunchKernelGGL(k_attn,  dim3(512), dim3(256), 0, stream, X, y_prev, W_fc, b_fc, ws);
    hipLaunchKernelGGL(k_lstm,  dim3(256), dim3(256), 0, stream, W_ih, b_ih, b_hh, ws);
    hipLaunchKernelGGL(k_final, dim3(512), dim3(256), 0, stream, W_fin, b_fin, (float*)d_out, ws);
}

// Round 2
// 723.295 us; speedup vs baseline: 6.4043x; 6.4043x over previous
//
#include <hip/hip_runtime.h>
#include <stdint.h>

typedef __attribute__((ext_vector_type(8))) short short8;
typedef __attribute__((ext_vector_type(4))) float floatx4;

#define T1 127
#define ENC 256
#define HD 256

// workspace offsets (bytes)
#define WHI_OFF   0u            // 1024*256 ushort = 524288
#define WLO_OFF   524288u
#define D0_OFF    1048576u      // 512*256 fp32 = 524288
#define D1_OFF    1572864u
#define WEFF_OFF  2097152u      // 256 floats
#define FLAGS_OFF 2098176u      // 256 u32
#define YT_OFF    2099200u      // 512*128 fp32 = 262144
#define CTX_OFF   2361344u      // 512*256 fp32 = 524288
#define DT_OFF    2885632u      // 512*256 fp32 = 524288

__device__ __forceinline__ void split_bf16(float x, unsigned& hi, unsigned& lo) {
    unsigned u = __float_as_uint(x);
    hi = u >> 16;
    float hf = __uint_as_float(hi << 16);
    float r = x - hf;
    unsigned ur = __float_as_uint(r);
    lo = (ur + 0x7fffu + ((ur >> 16) & 1u)) >> 16;
}

// ---------------- k_prep: weight collapse + W_hh hi/lo split + init ----------------
__global__ __launch_bounds__(256) void k_prep(const float* __restrict__ W1,
                                              const float* __restrict__ W2,
                                              const float* __restrict__ W_hh,
                                              char* __restrict__ ws) {
    const int tid = threadIdx.x, bid = blockIdx.x;
    ushort* Whi = (ushort*)(ws + WHI_OFF);
    ushort* Wlo = (ushort*)(ws + WLO_OFF);
    // split W_hh (1024x256): each thread one float4
    {
        const int i4 = bid * 256 + tid;   // 0..65535
        float4 v = ((const float4*)W_hh)[i4];
        float vv[4] = {v.x, v.y, v.z, v.w};
        unsigned h[4], l[4];
        #pragma unroll
        for (int j = 0; j < 4; ++j) split_bf16(vv[j], h[j], l[j]);
        *(ushort4*)(Whi + i4 * 4) = make_ushort4((ushort)h[0], (ushort)h[1], (ushort)h[2], (ushort)h[3]);
        *(ushort4*)(Wlo + i4 * 4) = make_ushort4((ushort)l[0], (ushort)l[1], (ushort)l[2], (ushort)l[3]);
    }
    // zero d buffer 0: 512*256 fp32 = 32768 uint4
    {
        const int idx = bid * 256 + tid;
        if (idx < 32768) ((uint4*)(ws + D0_OFF))[idx] = make_uint4(0, 0, 0, 0);
    }
    if (bid == 1) ((unsigned*)(ws + FLAGS_OFF))[tid] = 0u;
    if (bid == 0) {
        // collapsed attention weight: weff[e] = sum_j W2[j] * W1[j,512+e]
        float acc = 0.f;
        for (int j = 0; j < 128; ++j)
            acc = fmaf(W2[j], W1[j * 768 + 512 + tid], acc);
        ((float*)(ws + WEFF_OFF))[tid] = acc;
    }
}

// ---------------- k_attn: scores -> softmax -> context -> y_tilde ----------------
__global__ __launch_bounds__(256) void k_attn(const float* __restrict__ X,
                                              const float* __restrict__ y_prev,
                                              const float* __restrict__ W_fc,
                                              const float* __restrict__ b_fc,
                                              char* __restrict__ ws) {
    __shared__ float s_lds[128];
    __shared__ float beta[128];
    __shared__ float red[256];
    const int b = blockIdx.x, tid = threadIdx.x;
    const int w = tid >> 6, lane = tid & 63;
    const float* Xb = X + (size_t)b * T1 * ENC;
    const float* weff = (const float*)(ws + WEFF_OFF);
    const float4 w4 = ((const float4*)weff)[lane];
    for (int i = 0; i < 32; ++i) {
        int t = w * 32 + i;
        if (t >= T1) break;
        float4 x4 = ((const float4*)(Xb + t * ENC))[lane];
        float a = x4.x * w4.x + x4.y * w4.y + x4.z * w4.z + x4.w * w4.w;
        for (int m = 32; m >= 1; m >>= 1) a += __shfl_xor(a, m, 64);
        if (lane == 0) s_lds[t] = a;
    }
    __syncthreads();
    if (w == 0) {
        float v0 = s_lds[lane];
        float v1 = (lane + 64 < T1) ? s_lds[lane + 64] : -1e30f;
        float mx = fmaxf(v0, v1);
        for (int m = 32; m >= 1; m >>= 1) mx = fmaxf(mx, __shfl_xor(mx, m, 64));
        float e0 = __expf(v0 - mx);
        float e1 = (lane + 64 < T1) ? __expf(v1 - mx) : 0.f;
        float s = e0 + e1;
        for (int m = 32; m >= 1; m >>= 1) s += __shfl_xor(s, m, 64);
        float inv = 1.f / s;
        beta[lane] = e0 * inv;
        if (lane + 64 < T1) beta[lane + 64] = e1 * inv;
    }
    __syncthreads();
    // context[b, tid]
    float acc = 0.f;
    for (int t = 0; t < T1; ++t) acc = fmaf(beta[t], Xb[t * ENC + tid], acc);
    ((float*)(ws + CTX_OFF))[b * ENC + tid] = acc;
    // u = W_fc[0:256] . context + b_fc
    red[tid] = acc * W_fc[tid];
    __syncthreads();
    for (int s = 128; s >= 1; s >>= 1) { if (tid < s) red[tid] += red[tid + s]; __syncthreads(); }
    const float u = red[0] + b_fc[0];
    const float wy = W_fc[256];
    if (tid < T1)
        ((float*)(ws + YT_OFF))[b * 128 + tid] = u + wy * y_prev[b * T1 + tid];
}

// ---------------- k_lstm: persistent sequential LSTM, fence-free coherent exchange ----------------
// 256 blocks: gi = bid>>3 (32 batch groups x 16 batches), hj = bid&7 (8 h-tiles x 32 h).
// W slice (32h x 4 gates x 256k, hi+lo bf16) resident in VGPRs.
// d exchanged as raw fp32 via relaxed agent-scope atomics (device-coherent, NO fences).
__global__ __launch_bounds__(256, 1) void k_lstm(const float* __restrict__ W_ih,
                                                 const float* __restrict__ b_ih,
                                                 const float* __restrict__ b_hh,
                                                 char* __restrict__ ws) {
    __shared__ __align__(16) ushort ldh[16 * 264];
    __shared__ __align__(16) ushort ldl[16 * 264];
    __shared__ float gbuf[16 * 132];

    const int tid = threadIdx.x, bid = blockIdx.x;
    const int gi = bid >> 3, hj = bid & 7;
    const int w = tid >> 6, lane = tid & 63;
    const int n16 = lane & 15, q = lane >> 4;

    const ushort* Whi = (const ushort*)(ws + WHI_OFF);
    const ushort* Wlo = (const ushort*)(ws + WLO_OFF);
    unsigned* Dbuf0 = (unsigned*)(ws + D0_OFF);
    unsigned* Dbuf1 = (unsigned*)(ws + D1_OFF);
    const float* yt = (const float*)(ws + YT_OFF);
    unsigned* flags = (unsigned*)(ws + FLAGS_OFF);
    float* dT = (float*)(ws + DT_OFF);

    // resident W fragments: wave w owns N-tiles {2w, 2w+1}; row r = hloc*4 + g
    short8 bfh[2][8], bfl[2][8];
    #pragma unroll
    for (int j = 0; j < 2; ++j) {
        const int r = (2 * w + j) * 16 + n16;          // 0..127
        const int hloc = r >> 2, g = r & 3;
        const int R = g * 256 + hj * 32 + hloc;        // global gate row
        #pragma unroll
        for (int kt = 0; kt < 8; ++kt) {
            bfh[j][kt] = *(const short8*)(Whi + R * 256 + kt * 32 + q * 8);
            bfl[j][kt] = *(const short8*)(Wlo + R * 256 + kt * 32 + q * 8);
        }
    }

    // cell assignment: 16 batches x 32 h = 512 cells, 2 per thread
    const int b_loc = tid & 15, hpair = tid >> 4;      // hpair 0..15
    const int hloc0 = hpair * 2;
    const int bg = gi * 16 + b_loc;
    float wihr[2][4], bihr[2][4];
    #pragma unroll
    for (int jj = 0; jj < 2; ++jj)
        #pragma unroll
        for (int g = 0; g < 4; ++g) {
            const int row = g * HD + hj * 32 + hloc0 + jj;
            wihr[jj][g] = W_ih[row];
            bihr[jj][g] = b_ih[row] + b_hh[row];
        }
    float cc0 = 0.f, cc1 = 0.f;

    for (int t = 1; t <= T1; ++t) {
        // wait for all 8 blocks of this batch group to publish d_{t-1}
        if (t > 1) {
            if (w == 0) {
                const unsigned tgt = (unsigned)(t - 1);
                const unsigned fi = (unsigned)(gi * 8 + (lane & 7));
                for (;;) {
                    unsigned v = (lane < 8)
                        ? __hip_atomic_load(&flags[fi], __ATOMIC_RELAXED, __HIP_MEMORY_SCOPE_AGENT)
                        : tgt;
                    if (__all((int)(v >= tgt))) break;
                    __builtin_amdgcn_s_sleep(1);
                }
            }
            __syncthreads();
        }
        // stage d slab (16 rows x 256 fp32) via coherent loads; split to bf16 hi/lo in LDS
        {
            unsigned* Dsrc = ((t - 1) & 1) ? Dbuf1 : Dbuf0;
            unsigned uv[16];
            #pragma unroll
            for (int i = 0; i < 16; ++i)
                uv[i] = __hip_atomic_load(&Dsrc[(gi * 16 + i) * 256 + tid],
                                          __ATOMIC_RELAXED, __HIP_MEMORY_SCOPE_AGENT);
            #pragma unroll
            for (int i = 0; i < 16; ++i) {
                float v = __uint_as_float(uv[i]);
                unsigned h, l;
                split_bf16(v, h, l);
                ldh[i * 264 + tid] = (ushort)h;
                ldl[i * 264 + tid] = (ushort)l;
            }
        }
        __syncthreads();
        // MFMA: gates[16b x 128r] = d[16x256] @ Wslice^T  (hi*hi + lo*hi + hi*lo)
        floatx4 acc0 = {0.f, 0.f, 0.f, 0.f}, acc1 = {0.f, 0.f, 0.f, 0.f};
        #pragma unroll
        for (int kt = 0; kt < 8; ++kt) {
            short8 ah = *(const short8*)(ldh + n16 * 264 + kt * 32 + q * 8);
            short8 al = *(const short8*)(ldl + n16 * 264 + kt * 32 + q * 8);
            acc0 = __builtin_amdgcn_mfma_f32_16x16x32_bf16(ah, bfh[0][kt], acc0, 0, 0, 0);
            acc0 = __builtin_amdgcn_mfma_f32_16x16x32_bf16(al, bfh[0][kt], acc0, 0, 0, 0);
            acc0 = __builtin_amdgcn_mfma_f32_16x16x32_bf16(ah, bfl[0][kt], acc0, 0, 0, 0);
            acc1 = __builtin_amdgcn_mfma_f32_16x16x32_bf16(ah, bfh[1][kt], acc1, 0, 0, 0);
            acc1 = __builtin_amdgcn_mfma_f32_16x16x32_bf16(al, bfh[1][kt], acc1, 0, 0, 0);
            acc1 = __builtin_amdgcn_mfma_f32_16x16x32_bf16(ah, bfl[1][kt], acc1, 0, 0, 0);
        }
        // scatter C-frags: row m = q*4+reg (batch), col = tile*16+n16 (gate row)
        #pragma unroll
        for (int reg = 0; reg < 4; ++reg) {
            gbuf[(q * 4 + reg) * 132 + (2 * w) * 16 + n16]     = acc0[reg];
            gbuf[(q * 4 + reg) * 132 + (2 * w + 1) * 16 + n16] = acc1[reg];
        }
        __syncthreads();
        // LSTM cell: 2 cells per thread
        const float ytv = yt[bg * 128 + (t - 1)];
        float dnew[2];
        #pragma unroll
        for (int jj = 0; jj < 2; ++jj) {
            const int base = b_loc * 132 + (hloc0 + jj) * 4;
            float pi = gbuf[base + 0] + ytv * wihr[jj][0] + bihr[jj][0];
            float pf = gbuf[base + 1] + ytv * wihr[jj][1] + bihr[jj][1];
            float pg = gbuf[base + 2] + ytv * wihr[jj][2] + bihr[jj][2];
            float po = gbuf[base + 3] + ytv * wihr[jj][3] + bihr[jj][3];
            float ig = 1.f / (1.f + __expf(-pi));
            float fg = 1.f / (1.f + __expf(-pf));
            float gg = tanhf(pg);
            float og = 1.f / (1.f + __expf(-po));
            float& c = jj ? cc1 : cc0;
            c = fg * c + ig * gg;
            dnew[jj] = og * tanhf(c);
        }
        const int dbase = bg * 256 + hj * 32 + hloc0;
        if (t < T1) {
            unsigned* Ddst = (t & 1) ? Dbuf1 : Dbuf0;
            __hip_atomic_store(&Ddst[dbase],     __float_as_uint(dnew[0]),
                               __ATOMIC_RELAXED, __HIP_MEMORY_SCOPE_AGENT);
            __hip_atomic_store(&Ddst[dbase + 1], __float_as_uint(dnew[1]),
                               __ATOMIC_RELAXED, __HIP_MEMORY_SCOPE_AGENT);
            // drain coherent stores (device-visible once vmcnt retires), then signal
            asm volatile("s_waitcnt vmcnt(0)" ::: "memory");
            __syncthreads();
            if (tid == 0)
                __hip_atomic_store(&flags[bid], (unsigned)t,
                                   __ATOMIC_RELAXED, __HIP_MEMORY_SCOPE_AGENT);
        } else {
            dT[dbase] = dnew[0];
            dT[dbase + 1] = dnew[1];
        }
    }
}

// ---------------- k_final: y_pred = W_final . [dT, context] + b ----------------
__global__ __launch_bounds__(256) void k_final(const float* __restrict__ W_final,
                                               const float* __restrict__ b_final,
                                               float* __restrict__ out,
                                               char* __restrict__ ws) {
    __shared__ float red[256];
    const int b = blockIdx.x, tid = threadIdx.x;
    const float* dT = (const float*)(ws + DT_OFF);
    const float* ctx = (const float*)(ws + CTX_OFF);
    float v = W_final[tid] * dT[b * 256 + tid] + W_final[256 + tid] * ctx[b * 256 + tid];
    red[tid] = v;
    __syncthreads();
    for (int s = 128; s >= 1; s >>= 1) { if (tid < s) red[tid] += red[tid + s]; __syncthreads(); }
    if (tid == 0) out[b] = red[0] + b_final[0];
}

extern "C" void kernel_launch(void* const* d_in, const int* in_sizes, int n_in,
                              void* d_out, int out_size, void* d_ws, size_t ws_size,
                              hipStream_t stream) {
    const float* X      = (const float*)d_in[0];
    const float* y_prev = (const float*)d_in[1];
    const float* W1     = (const float*)d_in[2];
    const float* W2     = (const float*)d_in[4];
    const float* W_fc   = (const float*)d_in[6];
    const float* b_fc   = (const float*)d_in[7];
    const float* W_ih   = (const float*)d_in[8];
    const float* W_hh   = (const float*)d_in[9];
    const float* b_ih   = (const float*)d_in[10];
    const float* b_hh   = (const float*)d_in[11];
    const float* W_fin  = (const float*)d_in[12];
    const float* b_fin  = (const float*)d_in[13];
    char* ws = (char*)d_ws;

    hipLaunchKernelGGL(k_prep,  dim3(256), dim3(256), 0, stream, W1, W2, W_hh, ws);
    hipLaunchKernelGGL(k_attn,  dim3(512), dim3(256), 0, stream, X, y_prev, W_fc, b_fc, ws);
    hipLaunchKernelGGL(k_lstm,  dim3(256), dim3(256), 0, stream, W_ih, b_ih, b_hh, ws);
    hipLaunchKernelGGL(k_final, dim3(512), dim3(256), 0, stream, W_fin, b_fin, (float*)d_out, ws);
}